// Round 1
// baseline (201.546 us; speedup 1.0000x reference)
//
#include <hip/hip_runtime.h>

#define LN_EPS 1e-5f
#define SBSH   14             // superbucket = dst >> 14 (16384 nodes)
#define NSB    7              // ceil(100000 / 16384)
#define CAP1   268288         // per-SB capacity = 131*2048 (mean 262144 + ~13 sigma)
#define CPS    131            // CAP1 / 2048 chunks per SB (bin2 chunking)
#define BN     128            // nodes per final bucket
#define BC     2368           // bucket capacity (mean 2048 + 7 sigma, R8-proven)
#define NBK    782            // ceil(N / BN)
#define CSTRIDE 8

typedef __attribute__((ext_vector_type(8))) short short8;
typedef __attribute__((ext_vector_type(8))) unsigned short ushort8;
typedef __attribute__((ext_vector_type(4))) float v4f;

__device__ __forceinline__ unsigned short f2bf(float f) {
    union { float f; unsigned u; } v; v.f = f;
    unsigned r = (v.u + 0x7fffu + ((v.u >> 16) & 1u)) >> 16;   // RNE
    return (unsigned short)r;
}
__device__ __forceinline__ float bf2f(unsigned short h) {
    union { unsigned u; float f; } v; v.u = ((unsigned)h) << 16;
    return v.f;
}
// dword holds 2 bf16: lo = feature 2k, hi = feature 2k+1
__device__ __forceinline__ float bflo(unsigned v) {
    union { unsigned u; float f; } w; w.u = v << 16; return w.f;
}
__device__ __forceinline__ float bfhi(unsigned v) {
    union { unsigned u; float f; } w; w.u = v & 0xFFFF0000u; return w.f;
}

// ---------------- bin1: edges -> 7 superbuckets (+ WTB + x->bf16 + x->xs slices) ----
// 4096-edge chunks -> runs of ~585 ints per (chunk, sb) -> near-perfect lines.
// Histogram uses 8 COPIES (h[copy][sb], copy = t&7): 64 distinct LDS addresses
// instead of 8 -> ~8x less same-address atomic serialization (R10 lesson).
// NEW: also writes xs[phase][node][16] (4 x 3.2 MB feature slices) so the
// gather kernel can run phase-major with a per-phase footprint that FITS the
// 4 MB per-XCD L2 (xb row-major is 12.8 MB -> ~30% L2 hit, LLC-latency bound).
// xs writes are fully coalesced: per wave, 4 nodes x 32 B contiguous per phase
// region = 4 full 128-B lines.
__global__ __launch_bounds__(256) void bin1_kernel(
    const int* __restrict__ ei, int* __restrict__ cursor1,
    int* __restrict__ pairs1, const float* __restrict__ W,
    unsigned short* __restrict__ WTB, const float4* __restrict__ x4,
    ushort4* __restrict__ xb4, ushort4* __restrict__ xs4, int E, int N)
{
    __shared__ int h[64];       // [copy*8 + sb]
    __shared__ int hbase[64];
    int t = threadIdx.x;
    int cp = t & 7;

    if (blockIdx.x == 0) {
        // WTB: frag (s,tt), lane l, elem j <- W[o=tt*16+(l&15)][k=s*32+(l>>4)*8+j]
        for (int i = t; i < 8192; i += 256) {
            int j = i & 7, l = (i >> 3) & 63, st = i >> 9;
            int s = st >> 2, tt = st & 3;
            WTB[i] = f2bf(W[(tt * 16 + (l & 15)) * 128 + s * 32 + (l >> 4) * 8 + j]);
        }
    }
    {   // grid-stride x -> bf16 (row-major xb for linear, feature-sliced xs for gather)
        int total4 = N * 16;
        for (int i = blockIdx.x * 256 + t; i < total4; i += gridDim.x * 256) {
            float4 v = x4[i];
            ushort4 u;
            u.x = f2bf(v.x); u.y = f2bf(v.y); u.z = f2bf(v.z); u.w = f2bf(v.w);
            xb4[i] = u;
            int node = i >> 4, c = i & 15;            // c = 4-feature chunk 0..15
            xs4[(((c >> 2) * N + node) << 2) + (c & 3)] = u;   // phase = c>>2
        }
    }

    for (int i = t; i < 64; i += 256) h[i] = 0;
    __syncthreads();
    int e0 = blockIdx.x * 4096;
    int dstA[16], srcA[16], rkA[16];
    #pragma unroll
    for (int i = 0; i < 16; ++i) {
        int e = e0 + i * 256 + t;
        int dst = 0, src = 0, rk = -1;
        if (e < E) {
            dst = ei[e]; src = ei[E + e];
            if ((unsigned)dst < (unsigned)N) {
                rk = atomicAdd(&h[cp * 8 + (dst >> SBSH)], 1);
                if ((unsigned)src >= (unsigned)N) src = 0;   // replay-safe clamp
            } else { dst = 0; }
        }
        dstA[i] = dst; srcA[i] = src; rkA[i] = rk;
    }
    __syncthreads();
    if (t < 8) {    // per sb: total over copies, one global reservation, copy prefixes
        int tot = 0;
        #pragma unroll
        for (int c = 0; c < 8; ++c) tot += h[c * 8 + t];
        int gb = tot ? atomicAdd(&cursor1[t * 16], tot) : 0;
        int run = gb;
        #pragma unroll
        for (int c = 0; c < 8; ++c) { hbase[c * 8 + t] = run; run += h[c * 8 + t]; }
    }
    __syncthreads();
    #pragma unroll
    for (int i = 0; i < 16; ++i) {
        if (rkA[i] >= 0) {
            int sb = dstA[i] >> SBSH;
            int slot = hbase[cp * 8 + sb] + rkA[i];
            if (slot < CAP1)
                pairs1[(size_t)sb * CAP1 + slot] = ((dstA[i] & 16383) << 17) | srcA[i];
        }
    }
}

// ---------------- bin2: superbucket chunk -> 128-node buckets ----------------
// Runs of 2048/128 = 16 ints (one line). bucket-in-SB = (pv>>24)&127.
// pairs2 keeps low 24 bits: dl7 @17..23, src @0..16. cursor2 line-spread.
__global__ __launch_bounds__(256) void bin2_kernel(
    const int* __restrict__ cursor1, const int* __restrict__ pairs1,
    int* __restrict__ cursor2, int* __restrict__ pairs2)
{
    __shared__ int h[128], hbase[128];
    int t = threadIdx.x;
    int sb = blockIdx.x / CPS;
    int off0 = (blockIdx.x % CPS) * 2048;
    int tot = cursor1[sb * 16]; if (tot > CAP1) tot = CAP1;
    int m = tot - off0;
    if (m <= 0) return;                    // block-uniform
    if (m > 2048) m = 2048;
    if (t < 128) h[t] = 0;
    __syncthreads();
    const int* p1 = pairs1 + (size_t)sb * CAP1 + off0;
    int pvA[8], rkA[8];
    #pragma unroll
    for (int i = 0; i < 8; ++i) {
        int idx = i * 256 + t;
        int pv = 0, rk = -1;
        if (idx < m) { pv = p1[idx]; rk = atomicAdd(&h[(pv >> 24) & 127], 1); }
        pvA[i] = pv; rkA[i] = rk;
    }
    __syncthreads();
    if (t < 128) {
        int c = h[t];
        hbase[t] = c ? atomicAdd(&cursor2[(sb * 128 + t) * CSTRIDE], c) : 0;
    }
    __syncthreads();
    #pragma unroll
    for (int i = 0; i < 8; ++i) {
        if (rkA[i] >= 0) {
            int bl = (pvA[i] >> 24) & 127;
            int g = sb * 128 + bl;
            int slot = hbase[bl] + rkA[i];
            if (g < NBK && slot < BC)
                pairs2[(size_t)g * BC + slot] = pvA[i] & 0xFFFFFF;
        }
    }
}

// ---------------- sortgather: LDS counting sort + PHASED group-per-node gather ----
// 1024 threads (16 waves), ~11 KB LDS, low VGPR -> 2 blocks/CU (full 32 waves).
// Sort = R8's proven counting sort (srcS stays in LDS). Gather v3: the random
// gather now runs in 4 feature phases over xs[phase][node][16]; each phase's
// random footprint is 3.2 MB < 4 MB per-XCD L2, so requests hit L2 (~200 cyc)
// instead of LLC (~400-900 cyc). Each 8-lane group owns one node; per edge per
// phase each lane loads ONE dword (2 bf16 feats) -> one coalesced 32-B request
// per group. 4-edge unroll keeps 4 independent loads in flight per lane; srcS
// re-read per phase is free (LDS). aggb row-major preserved for linear.
__global__ __launch_bounds__(1024) void sortgather_kernel(
    const int* __restrict__ cursor2, const int* __restrict__ pairs2,
    const unsigned short* __restrict__ xs, unsigned short* __restrict__ aggb, int N)
{
    __shared__ int srcS[BC];                 // 9.47 KB
    __shared__ int cnt[BN], off[BN], cur[BN];
    int t = threadIdx.x;
    int g = blockIdx.x;
    int bsize = cursor2[g * CSTRIDE]; if (bsize > BC) bsize = BC;
    const int* pb = pairs2 + (size_t)g * BC;

    if (t < BN) cnt[t] = 0;
    __syncthreads();
    for (int i = t; i < bsize; i += 1024) atomicAdd(&cnt[(pb[i] >> 17) & 127], 1);
    __syncthreads();
    if (t < BN) off[t] = cnt[t];
    __syncthreads();
    for (int s = 1; s < BN; s <<= 1) {
        int v = (t < BN && t >= s) ? off[t - s] : 0;
        __syncthreads();
        if (t < BN) off[t] += v;
        __syncthreads();
    }
    if (t < BN) { int ex = off[t] - cnt[t]; off[t] = ex; cur[t] = ex; }
    __syncthreads();
    for (int i = t; i < bsize; i += 1024) {
        int p = pb[i];
        int pos = atomicAdd(&cur[(p >> 17) & 127], 1);
        srcS[pos] = p & 0x1FFFF;
    }
    __syncthreads();

    int lane = t & 63, wv = t >> 6;          // 16 waves x 8 groups = 128 nodes
    int g8 = lane >> 3, f8 = lane & 7;
    int ln = wv * 8 + g8;                    // this group's node (bucket-local)
    int deg = cnt[ln], base = off[ln];
    int node = g * BN + ln;
    float inv = 1.0f / fmaxf((float)deg, 1.0f);

    const unsigned* xs32 = (const unsigned*)xs;   // dword view: (p*N+src)*8 + f8

    #pragma unroll
    for (int p = 0; p < 4; ++p) {
        size_t pbase = (size_t)p * N * 8;
        float a0 = 0.f, a1 = 0.f;
        int j = 0;
        for (; j + 4 <= deg; j += 4) {       // 4 independent loads in flight
            int s0 = srcS[base + j];
            int s1 = srcS[base + j + 1];
            int s2 = srcS[base + j + 2];
            int s3 = srcS[base + j + 3];
            unsigned v0 = xs32[pbase + (size_t)s0 * 8 + f8];
            unsigned v1 = xs32[pbase + (size_t)s1 * 8 + f8];
            unsigned v2 = xs32[pbase + (size_t)s2 * 8 + f8];
            unsigned v3 = xs32[pbase + (size_t)s3 * 8 + f8];
            a0 += bflo(v0); a1 += bfhi(v0);
            a0 += bflo(v1); a1 += bfhi(v1);
            a0 += bflo(v2); a1 += bfhi(v2);
            a0 += bflo(v3); a1 += bfhi(v3);
        }
        for (; j < deg; ++j) {
            int s0 = srcS[base + j];
            unsigned v0 = xs32[pbase + (size_t)s0 * 8 + f8];
            a0 += bflo(v0); a1 += bfhi(v0);
        }
        if (node < N) {
            unsigned pk = (unsigned)f2bf(a0 * inv) | ((unsigned)f2bf(a1 * inv) << 16);
            *(unsigned*)(aggb + (size_t)node * 64 + p * 16 + f8 * 2) = pk;
        }
    }
}

// ---------------- linear + ReLU + LN via bf16 MFMA (R8 verbatim) ----------------
__global__ __launch_bounds__(256) void linear_kernel(
    const unsigned short* __restrict__ xb, const unsigned short* __restrict__ aggb,
    const unsigned short* __restrict__ WTB, const float* __restrict__ b,
    const float* __restrict__ gamma, const float* __restrict__ beta,
    float* __restrict__ out, int N)
{
    int lane = threadIdx.x & 63;
    int wv   = threadIdx.x >> 6;
    int nb   = blockIdx.x * 64 + wv * 16;
    if (nb >= N) return;
    int c = lane & 15, q = lane >> 4;
    int nm = nb + c; if (nm >= N) nm = N - 1;

    short8 bf[4][4];
    const short8* WB = (const short8*)WTB;
    #pragma unroll
    for (int s = 0; s < 4; ++s)
        #pragma unroll
        for (int tt = 0; tt < 4; ++tt)
            bf[s][tt] = WB[(s * 4 + tt) * 64 + lane];

    v4f acc[4];
    #pragma unroll
    for (int tt = 0; tt < 4; ++tt) acc[tt] = 0.f;

    #pragma unroll
    for (int s = 0; s < 2; ++s) {
        short8 af = *(const short8*)(xb + (size_t)nm * 64 + s * 32 + q * 8);
        #pragma unroll
        for (int tt = 0; tt < 4; ++tt)
            acc[tt] = __builtin_amdgcn_mfma_f32_16x16x32_bf16(af, bf[s][tt], acc[tt], 0, 0, 0);
    }
    #pragma unroll
    for (int s = 0; s < 2; ++s) {
        short8 af = *(const short8*)(aggb + (size_t)nm * 64 + s * 32 + q * 8);
        #pragma unroll
        for (int tt = 0; tt < 4; ++tt)
            acc[tt] = __builtin_amdgcn_mfma_f32_16x16x32_bf16(af, bf[2 + s][tt], acc[tt], 0, 0, 0);
    }

    float bb[4], gg[4], be[4];
    #pragma unroll
    for (int tt = 0; tt < 4; ++tt) {
        bb[tt] = b[tt * 16 + c];
        gg[tt] = gamma[tt * 16 + c];
        be[tt] = beta[tt * 16 + c];
    }
    #pragma unroll
    for (int r = 0; r < 4; ++r) {
        int node = nb + q * 4 + r;
        float v[4]; float s0 = 0.f, q0 = 0.f;
        #pragma unroll
        for (int tt = 0; tt < 4; ++tt) {
            float vv = acc[tt][r] + bb[tt];
            vv = fmaxf(vv, 0.f);
            v[tt] = vv; s0 += vv; q0 += vv * vv;
        }
        #pragma unroll
        for (int o = 1; o <= 8; o <<= 1) {
            s0 += __shfl_xor(s0, o);
            q0 += __shfl_xor(q0, o);
        }
        float mu  = s0 * (1.0f / 64.0f);
        float var = q0 * (1.0f / 64.0f) - mu * mu;
        float rs  = rsqrtf(var + LN_EPS);
        if (node < N) {
            #pragma unroll
            for (int tt = 0; tt < 4; ++tt)
                out[(size_t)node * 64 + tt * 16 + c] = (v[tt] - mu) * rs * gg[tt] + be[tt];
        }
    }
}

extern "C" void kernel_launch(void* const* d_in, const int* in_sizes, int n_in,
                              void* d_out, int out_size, void* d_ws, size_t ws_size,
                              hipStream_t stream)
{
    const float* x     = (const float*)d_in[0];
    const int*   ei    = (const int*)d_in[1];
    const float* W     = (const float*)d_in[2];
    const float* b     = (const float*)d_in[3];
    const float* gamma = (const float*)d_in[4];
    const float* beta  = (const float*)d_in[5];

    int N = in_sizes[0] / 64;      // 100000
    int E = in_sizes[1] / 2;       // 1600000

    // ws (ints): cursor1[128] | cursor2[896*8] | WTB[4096] | pairs2[NBK*BC]
    //            | xb (bf16 row-major, 12.8 MB) | xs (bf16 4x feature slices, 12.8 MB)
    int* wsI = (int*)d_ws;
    int* cursor1 = wsI;
    int* cursor2 = wsI + 128;
    unsigned short* WTB = (unsigned short*)(wsI + 128 + 896 * CSTRIDE);
    int* pairs2 = wsI + 128 + 896 * CSTRIDE + 4096;
    unsigned short* xb = (unsigned short*)(pairs2 + (size_t)NBK * BC);
    unsigned short* xs = xb + (size_t)N * 64;

    // pairs1 lives in d_out (7.5 MB of 25.6 MB), dead after bin2, before linear writes
    int* pairs1 = (int*)d_out;
    // ei dead after bin1 -> bf16 agg (N*64*2B exact fit; harness restores ei pre-launch)
    unsigned short* aggb = (unsigned short*)d_in[1];

    float* out = (float*)d_out;

    hipMemsetAsync(cursor1, 0, (size_t)(128 + 896 * CSTRIDE) * sizeof(int), stream);

    int b1 = (E + 4095) / 4096;        // 391
    bin1_kernel<<<b1, 256, 0, stream>>>(ei, cursor1, pairs1, W, WTB,
                                        (const float4*)x, (ushort4*)xb, (ushort4*)xs, E, N);

    bin2_kernel<<<NSB * CPS, 256, 0, stream>>>(cursor1, pairs1, cursor2, pairs2);

    sortgather_kernel<<<NBK, 1024, 0, stream>>>(cursor2, pairs2, xs, aggb, N);

    int lb = (N + 63) / 64;            // 1563
    linear_kernel<<<lb, 256, 0, stream>>>(xb, aggb, WTB, b, gamma, beta, out, N);
}

// Round 2
// 167.488 us; speedup vs baseline: 1.2033x; 1.2033x over previous
//
#include <hip/hip_runtime.h>

#define LN_EPS 1e-5f
#define SBSH   14             // superbucket = dst >> 14 (16384 nodes)
#define NSB    7              // ceil(100000 / 16384)
#define CAP1   268288         // per-SB capacity = 131*2048 (mean 262144 + ~13 sigma)
#define CPS    131            // CAP1 / 2048 chunks per SB (bin2 chunking)
#define BN     128            // nodes per final bucket
#define BC     2368           // bucket capacity (mean 2048 + 7 sigma, R8-proven)
#define NBK    782            // ceil(N / BN)
#define CSTRIDE 8
#define ASTR   72             // aggS row stride in bf16 (144 B -> 4-bank row shift, 2-way max)

typedef __attribute__((ext_vector_type(8))) short short8;
typedef __attribute__((ext_vector_type(8))) unsigned short ushort8;
typedef __attribute__((ext_vector_type(4))) float v4f;

__device__ __forceinline__ unsigned short f2bf(float f) {
    union { float f; unsigned u; } v; v.f = f;
    unsigned r = (v.u + 0x7fffu + ((v.u >> 16) & 1u)) >> 16;   // RNE
    return (unsigned short)r;
}
__device__ __forceinline__ float bf2f(unsigned short h) {
    union { unsigned u; float f; } v; v.u = ((unsigned)h) << 16;
    return v.f;
}

// ---------------- bin1: edges -> 7 superbuckets (+ WTB + x->bf16) ----------------
// Round-0 proven version (xs slices REMOVED: phased gather failed -- blocks are
// not phase-synchronized, so the per-XCD footprint stayed 12.8 MB and FETCH was
// 170 MB; the 32-B requests also wasted 64-B line fills).
__global__ __launch_bounds__(256) void bin1_kernel(
    const int* __restrict__ ei, int* __restrict__ cursor1,
    int* __restrict__ pairs1, const float* __restrict__ W,
    unsigned short* __restrict__ WTB, const float4* __restrict__ x4,
    ushort4* __restrict__ xb4, int E, int N)
{
    __shared__ int h[64];       // [copy*8 + sb]
    __shared__ int hbase[64];
    int t = threadIdx.x;
    int cp = t & 7;

    if (blockIdx.x == 0) {
        // WTB: frag (s,tt), lane l, elem j <- W[o=tt*16+(l&15)][k=s*32+(l>>4)*8+j]
        for (int i = t; i < 8192; i += 256) {
            int j = i & 7, l = (i >> 3) & 63, st = i >> 9;
            int s = st >> 2, tt = st & 3;
            WTB[i] = f2bf(W[(tt * 16 + (l & 15)) * 128 + s * 32 + (l >> 4) * 8 + j]);
        }
    }
    {   // grid-stride x -> bf16
        int total4 = N * 16;
        for (int i = blockIdx.x * 256 + t; i < total4; i += gridDim.x * 256) {
            float4 v = x4[i];
            ushort4 u;
            u.x = f2bf(v.x); u.y = f2bf(v.y); u.z = f2bf(v.z); u.w = f2bf(v.w);
            xb4[i] = u;
        }
    }

    for (int i = t; i < 64; i += 256) h[i] = 0;
    __syncthreads();
    int e0 = blockIdx.x * 4096;
    int dstA[16], srcA[16], rkA[16];
    #pragma unroll
    for (int i = 0; i < 16; ++i) {
        int e = e0 + i * 256 + t;
        int dst = 0, src = 0, rk = -1;
        if (e < E) {
            dst = ei[e]; src = ei[E + e];
            if ((unsigned)dst < (unsigned)N) {
                rk = atomicAdd(&h[cp * 8 + (dst >> SBSH)], 1);
                if ((unsigned)src >= (unsigned)N) src = 0;   // replay-safe clamp
            } else { dst = 0; }
        }
        dstA[i] = dst; srcA[i] = src; rkA[i] = rk;
    }
    __syncthreads();
    if (t < 8) {    // per sb: total over copies, one global reservation, copy prefixes
        int tot = 0;
        #pragma unroll
        for (int c = 0; c < 8; ++c) tot += h[c * 8 + t];
        int gb = tot ? atomicAdd(&cursor1[t * 16], tot) : 0;
        int run = gb;
        #pragma unroll
        for (int c = 0; c < 8; ++c) { hbase[c * 8 + t] = run; run += h[c * 8 + t]; }
    }
    __syncthreads();
    #pragma unroll
    for (int i = 0; i < 16; ++i) {
        if (rkA[i] >= 0) {
            int sb = dstA[i] >> SBSH;
            int slot = hbase[cp * 8 + sb] + rkA[i];
            if (slot < CAP1)
                pairs1[(size_t)sb * CAP1 + slot] = ((dstA[i] & 16383) << 17) | srcA[i];
        }
    }
}

// ---------------- bin2: superbucket chunk -> 128-node buckets ----------------
__global__ __launch_bounds__(256) void bin2_kernel(
    const int* __restrict__ cursor1, const int* __restrict__ pairs1,
    int* __restrict__ cursor2, int* __restrict__ pairs2)
{
    __shared__ int h[128], hbase[128];
    int t = threadIdx.x;
    int sb = blockIdx.x / CPS;
    int off0 = (blockIdx.x % CPS) * 2048;
    int tot = cursor1[sb * 16]; if (tot > CAP1) tot = CAP1;
    int m = tot - off0;
    if (m <= 0) return;                    // block-uniform
    if (m > 2048) m = 2048;
    if (t < 128) h[t] = 0;
    __syncthreads();
    const int* p1 = pairs1 + (size_t)sb * CAP1 + off0;
    int pvA[8], rkA[8];
    #pragma unroll
    for (int i = 0; i < 8; ++i) {
        int idx = i * 256 + t;
        int pv = 0, rk = -1;
        if (idx < m) { pv = p1[idx]; rk = atomicAdd(&h[(pv >> 24) & 127], 1); }
        pvA[i] = pv; rkA[i] = rk;
    }
    __syncthreads();
    if (t < 128) {
        int c = h[t];
        hbase[t] = c ? atomicAdd(&cursor2[(sb * 128 + t) * CSTRIDE], c) : 0;
    }
    __syncthreads();
    #pragma unroll
    for (int i = 0; i < 8; ++i) {
        if (rkA[i] >= 0) {
            int bl = (pvA[i] >> 24) & 127;
            int g = sb * 128 + bl;
            int slot = hbase[bl] + rkA[i];
            if (g < NBK && slot < BC)
                pairs2[(size_t)g * BC + slot] = pvA[i] & 0xFFFFFF;
        }
    }
}

// ---- fused sortgather + linear + ReLU + LN ----
// Sort + gather = R8/round-0 proven structure (short8 per lane, one full 128-B
// line per edge-group, 2 chained loads in flight x 8 groups/wave). NEW: the
// block's 128 aggregated nodes are exactly linear's tile, so the MFMA epilogue
// runs here on LDS-resident agg (bf16 aggS, row stride 72 = 144 B so row-to-row
// bank shift is 4 -> worst 2-way conflict, free per G4). Saves the 25.6 MB aggb
// HBM round-trip, one launch, and the ei-alias hack. __launch_bounds__(1024,8)
// pins VGPR<=64 -> 2 blocks/CU stays guaranteed for the gather phase.
__global__ __launch_bounds__(1024, 8) void sortgather_kernel(
    const int* __restrict__ cursor2, const int* __restrict__ pairs2,
    const unsigned short* __restrict__ xb, const unsigned short* __restrict__ WTB,
    const float* __restrict__ b, const float* __restrict__ gamma,
    const float* __restrict__ beta, float* __restrict__ out, int N)
{
    __shared__ int srcS[BC];                         // 9.47 KB
    __shared__ int cnt[BN], off[BN], cur[BN];        // 1.5 KB
    __shared__ __align__(16) unsigned short aggS[BN * ASTR];   // 18 KB
    int t = threadIdx.x;
    int g = blockIdx.x;
    int bsize = cursor2[g * CSTRIDE]; if (bsize > BC) bsize = BC;
    const int* pb = pairs2 + (size_t)g * BC;

    if (t < BN) cnt[t] = 0;
    __syncthreads();
    for (int i = t; i < bsize; i += 1024) atomicAdd(&cnt[(pb[i] >> 17) & 127], 1);
    __syncthreads();
    if (t < BN) off[t] = cnt[t];
    __syncthreads();
    for (int s = 1; s < BN; s <<= 1) {
        int v = (t < BN && t >= s) ? off[t - s] : 0;
        __syncthreads();
        if (t < BN) off[t] += v;
        __syncthreads();
    }
    if (t < BN) { int ex = off[t] - cnt[t]; off[t] = ex; cur[t] = ex; }
    __syncthreads();
    for (int i = t; i < bsize; i += 1024) {
        int p = pb[i];
        int pos = atomicAdd(&cur[(p >> 17) & 127], 1);
        srcS[pos] = p & 0x1FFFF;
    }
    __syncthreads();

    int lane = t & 63, wv = t >> 6;          // 16 waves x 8 groups = 128 nodes
    int g8 = lane >> 3, f8 = lane & 7;
    int ln = wv * 8 + g8;                    // this group's node (bucket-local)
    int deg = cnt[ln], base = off[ln];

    float acc[8];
    #pragma unroll
    for (int k = 0; k < 8; ++k) acc[k] = 0.f;

    int j = 0;
    for (; j + 2 <= deg; j += 2) {           // 2 loads in flight per group
        int s0 = srcS[base + j];
        int s1 = srcS[base + j + 1];
        short8 a0 = *(const short8*)(xb + (size_t)s0 * 64 + f8 * 8);
        short8 a1 = *(const short8*)(xb + (size_t)s1 * 64 + f8 * 8);
        #pragma unroll
        for (int k = 0; k < 8; ++k) acc[k] += bf2f((unsigned short)a0[k]);
        #pragma unroll
        for (int k = 0; k < 8; ++k) acc[k] += bf2f((unsigned short)a1[k]);
    }
    if (j < deg) {
        int s0 = srcS[base + j];
        short8 a0 = *(const short8*)(xb + (size_t)s0 * 64 + f8 * 8);
        #pragma unroll
        for (int k = 0; k < 8; ++k) acc[k] += bf2f((unsigned short)a0[k]);
    }

    {   // agg (mean) -> LDS bf16, row = bucket-local node, stride 72
        float inv = 1.0f / fmaxf((float)deg, 1.0f);
        ushort8 r;
        #pragma unroll
        for (int k = 0; k < 8; ++k) r[k] = f2bf(acc[k] * inv);
        *(ushort8*)(aggS + ln * ASTR + f8 * 8) = r;   // 144-B rows: 16-B aligned
    }
    __syncthreads();

    // ---- linear epilogue: waves 0..7, wave wv -> nodes [g*128+wv*16, +16) ----
    if (wv < 8) {
        int c = lane & 15, q = lane >> 4;
        int nb = g * BN + wv * 16;
        int nm = nb + c; if (nm >= N) nm = N - 1;
        int lnl = wv * 16 + c;               // bucket-local node for aggS

        const short8* WB = (const short8*)WTB;
        v4f acc4[4];
        #pragma unroll
        for (int tt = 0; tt < 4; ++tt) acc4[tt] = 0.f;

        #pragma unroll
        for (int s = 0; s < 2; ++s) {
            short8 af = *(const short8*)(xb + (size_t)nm * 64 + s * 32 + q * 8);
            #pragma unroll
            for (int tt = 0; tt < 4; ++tt)
                acc4[tt] = __builtin_amdgcn_mfma_f32_16x16x32_bf16(
                    af, WB[(s * 4 + tt) * 64 + lane], acc4[tt], 0, 0, 0);
        }
        #pragma unroll
        for (int s = 0; s < 2; ++s) {
            short8 af = *(const short8*)(aggS + lnl * ASTR + s * 32 + q * 8);
            #pragma unroll
            for (int tt = 0; tt < 4; ++tt)
                acc4[tt] = __builtin_amdgcn_mfma_f32_16x16x32_bf16(
                    af, WB[((2 + s) * 4 + tt) * 64 + lane], acc4[tt], 0, 0, 0);
        }

        float bb[4], gg[4], be[4];
        #pragma unroll
        for (int tt = 0; tt < 4; ++tt) {
            bb[tt] = b[tt * 16 + c];
            gg[tt] = gamma[tt * 16 + c];
            be[tt] = beta[tt * 16 + c];
        }
        #pragma unroll
        for (int r = 0; r < 4; ++r) {
            int node = nb + q * 4 + r;
            float v[4]; float s0 = 0.f, q0 = 0.f;
            #pragma unroll
            for (int tt = 0; tt < 4; ++tt) {
                float vv = acc4[tt][r] + bb[tt];
                vv = fmaxf(vv, 0.f);
                v[tt] = vv; s0 += vv; q0 += vv * vv;
            }
            #pragma unroll
            for (int o = 1; o <= 8; o <<= 1) {
                s0 += __shfl_xor(s0, o);
                q0 += __shfl_xor(q0, o);
            }
            float mu  = s0 * (1.0f / 64.0f);
            float var = q0 * (1.0f / 64.0f) - mu * mu;
            float rs  = rsqrtf(var + LN_EPS);
            if (node < N) {
                #pragma unroll
                for (int tt = 0; tt < 4; ++tt)
                    out[(size_t)node * 64 + tt * 16 + c] = (v[tt] - mu) * rs * gg[tt] + be[tt];
            }
        }
    }
}

extern "C" void kernel_launch(void* const* d_in, const int* in_sizes, int n_in,
                              void* d_out, int out_size, void* d_ws, size_t ws_size,
                              hipStream_t stream)
{
    const float* x     = (const float*)d_in[0];
    const int*   ei    = (const int*)d_in[1];
    const float* W     = (const float*)d_in[2];
    const float* b     = (const float*)d_in[3];
    const float* gamma = (const float*)d_in[4];
    const float* beta  = (const float*)d_in[5];

    int N = in_sizes[0] / 64;      // 100000
    int E = in_sizes[1] / 2;       // 1600000

    // ws (ints): cursor1[128] | cursor2[896*8] | WTB[4096] | pairs2[NBK*BC] | xb (bf16)
    int* wsI = (int*)d_ws;
    int* cursor1 = wsI;
    int* cursor2 = wsI + 128;
    unsigned short* WTB = (unsigned short*)(wsI + 128 + 896 * CSTRIDE);
    int* pairs2 = wsI + 128 + 896 * CSTRIDE + 4096;
    unsigned short* xb = (unsigned short*)(pairs2 + (size_t)NBK * BC);

    // pairs1 lives in d_out (7.5 MB of 25.6 MB), dead after bin2; the fused
    // sortgather then overwrites d_out with the final f32 output. ei untouched.
    int* pairs1 = (int*)d_out;
    float* out = (float*)d_out;

    hipMemsetAsync(cursor1, 0, (size_t)(128 + 896 * CSTRIDE) * sizeof(int), stream);

    int b1 = (E + 4095) / 4096;        // 391
    bin1_kernel<<<b1, 256, 0, stream>>>(ei, cursor1, pairs1, W, WTB,
                                        (const float4*)x, (ushort4*)xb, E, N);

    bin2_kernel<<<NSB * CPS, 256, 0, stream>>>(cursor1, pairs1, cursor2, pairs2);

    sortgather_kernel<<<NBK, 1024, 0, stream>>>(cursor2, pairs2, xb, WTB,
                                                b, gamma, beta, out, N);
}

// Round 3
// 166.045 us; speedup vs baseline: 1.2138x; 1.0087x over previous
//
#include <hip/hip_runtime.h>

#define LN_EPS 1e-5f
#define SBSH   14             // superbucket = dst >> 14 (16384 nodes)
#define NSB    7              // ceil(100000 / 16384)
#define CAP1   268288         // per-SB capacity = 131*2048 (mean 262144 + ~13 sigma)
#define CPS    131            // CAP1 / 2048 chunks per SB (bin2 chunking)
#define BN     128            // nodes per final bucket
#define BC     2368           // bucket capacity (mean 2048 + 7 sigma, R8-proven)
#define NBK    782            // ceil(N / BN)
#define CSTRIDE 8
#define ASTR   72             // aggS row stride in bf16 (144 B -> 4-bank row shift, 2-way max)

typedef __attribute__((ext_vector_type(8))) short short8;
typedef __attribute__((ext_vector_type(8))) unsigned short ushort8;
typedef __attribute__((ext_vector_type(4))) float v4f;

__device__ __forceinline__ unsigned short f2bf(float f) {
    union { float f; unsigned u; } v; v.f = f;
    unsigned r = (v.u + 0x7fffu + ((v.u >> 16) & 1u)) >> 16;   // RNE
    return (unsigned short)r;
}
__device__ __forceinline__ float bf2f(unsigned short h) {
    union { unsigned u; float f; } v; v.u = ((unsigned)h) << 16;
    return v.f;
}

// ---------------- bin1: edges -> 7 superbuckets (+ WTB + x->bf16) ----------------
__global__ __launch_bounds__(256) void bin1_kernel(
    const int* __restrict__ ei, int* __restrict__ cursor1,
    int* __restrict__ pairs1, const float* __restrict__ W,
    unsigned short* __restrict__ WTB, const float4* __restrict__ x4,
    ushort4* __restrict__ xb4, int E, int N)
{
    __shared__ int h[64];       // [copy*8 + sb]
    __shared__ int hbase[64];
    int t = threadIdx.x;
    int cp = t & 7;

    if (blockIdx.x == 0) {
        // WTB: frag (s,tt), lane l, elem j <- W[o=tt*16+(l&15)][k=s*32+(l>>4)*8+j]
        for (int i = t; i < 8192; i += 256) {
            int j = i & 7, l = (i >> 3) & 63, st = i >> 9;
            int s = st >> 2, tt = st & 3;
            WTB[i] = f2bf(W[(tt * 16 + (l & 15)) * 128 + s * 32 + (l >> 4) * 8 + j]);
        }
    }
    {   // grid-stride x -> bf16
        int total4 = N * 16;
        for (int i = blockIdx.x * 256 + t; i < total4; i += gridDim.x * 256) {
            float4 v = x4[i];
            ushort4 u;
            u.x = f2bf(v.x); u.y = f2bf(v.y); u.z = f2bf(v.z); u.w = f2bf(v.w);
            xb4[i] = u;
        }
    }

    for (int i = t; i < 64; i += 256) h[i] = 0;
    __syncthreads();
    int e0 = blockIdx.x * 4096;
    int dstA[16], srcA[16], rkA[16];
    #pragma unroll
    for (int i = 0; i < 16; ++i) {
        int e = e0 + i * 256 + t;
        int dst = 0, src = 0, rk = -1;
        if (e < E) {
            dst = ei[e]; src = ei[E + e];
            if ((unsigned)dst < (unsigned)N) {
                rk = atomicAdd(&h[cp * 8 + (dst >> SBSH)], 1);
                if ((unsigned)src >= (unsigned)N) src = 0;   // replay-safe clamp
            } else { dst = 0; }
        }
        dstA[i] = dst; srcA[i] = src; rkA[i] = rk;
    }
    __syncthreads();
    if (t < 8) {    // per sb: total over copies, one global reservation, copy prefixes
        int tot = 0;
        #pragma unroll
        for (int c = 0; c < 8; ++c) tot += h[c * 8 + t];
        int gb = tot ? atomicAdd(&cursor1[t * 16], tot) : 0;
        int run = gb;
        #pragma unroll
        for (int c = 0; c < 8; ++c) { hbase[c * 8 + t] = run; run += h[c * 8 + t]; }
    }
    __syncthreads();
    #pragma unroll
    for (int i = 0; i < 16; ++i) {
        if (rkA[i] >= 0) {
            int sb = dstA[i] >> SBSH;
            int slot = hbase[cp * 8 + sb] + rkA[i];
            if (slot < CAP1)
                pairs1[(size_t)sb * CAP1 + slot] = ((dstA[i] & 16383) << 17) | srcA[i];
        }
    }
}

// ---------------- bin2: superbucket chunk -> 128-node buckets ----------------
__global__ __launch_bounds__(256) void bin2_kernel(
    const int* __restrict__ cursor1, const int* __restrict__ pairs1,
    int* __restrict__ cursor2, int* __restrict__ pairs2)
{
    __shared__ int h[128], hbase[128];
    int t = threadIdx.x;
    int sb = blockIdx.x / CPS;
    int off0 = (blockIdx.x % CPS) * 2048;
    int tot = cursor1[sb * 16]; if (tot > CAP1) tot = CAP1;
    int m = tot - off0;
    if (m <= 0) return;                    // block-uniform
    if (m > 2048) m = 2048;
    if (t < 128) h[t] = 0;
    __syncthreads();
    const int* p1 = pairs1 + (size_t)sb * CAP1 + off0;
    int pvA[8], rkA[8];
    #pragma unroll
    for (int i = 0; i < 8; ++i) {
        int idx = i * 256 + t;
        int pv = 0, rk = -1;
        if (idx < m) { pv = p1[idx]; rk = atomicAdd(&h[(pv >> 24) & 127], 1); }
        pvA[i] = pv; rkA[i] = rk;
    }
    __syncthreads();
    if (t < 128) {
        int c = h[t];
        hbase[t] = c ? atomicAdd(&cursor2[(sb * 128 + t) * CSTRIDE], c) : 0;
    }
    __syncthreads();
    #pragma unroll
    for (int i = 0; i < 8; ++i) {
        if (rkA[i] >= 0) {
            int bl = (pvA[i] >> 24) & 127;
            int g = sb * 128 + bl;
            int slot = hbase[bl] + rkA[i];
            if (g < NBK && slot < BC)
                pairs2[(size_t)g * BC + slot] = pvA[i] & 0xFFFFFF;
        }
    }
}

// ---- fused sortgather + linear + ReLU + LN (v2: barrier-lean sort) ----
// Round-2 post-mortem: the old counting sort ran ~25 sixteen-wave barriers
// (histogram pass + 14-barrier scan + cur init + scatter) and read pb twice.
// New structure = bin2 pattern: ONE pass saving (pv, rank) in registers, a
// single-wave 128-bin prefix scan via __shfl_up (zero barriers), direct
// scatter at off[bin]+rank. 5 barriers total. Gather deepened to 4 loads in
// flight per group (VGPR still < 64 -> 2 blocks/CU at 1024 threads holds).
__global__ __launch_bounds__(1024, 8) void sortgather_kernel(
    const int* __restrict__ cursor2, const int* __restrict__ pairs2,
    const unsigned short* __restrict__ xb, const unsigned short* __restrict__ WTB,
    const float* __restrict__ b, const float* __restrict__ gamma,
    const float* __restrict__ beta, float* __restrict__ out, int N)
{
    __shared__ int srcS[BC];                         // 9.47 KB
    __shared__ int cnt[BN], off[BN];                 // 1 KB
    __shared__ __align__(16) unsigned short aggS[BN * ASTR];   // 18 KB
    int t = threadIdx.x;
    int g = blockIdx.x;
    int bsize = cursor2[g * CSTRIDE]; if (bsize > BC) bsize = BC;
    const int* pb = pairs2 + (size_t)g * BC;

    if (t < BN) cnt[t] = 0;
    __syncthreads();
    // single histogram+rank pass (pb read ONCE; rank kept in registers)
    int pvA[3], rkA[3];
    #pragma unroll
    for (int i = 0; i < 3; ++i) {
        int idx = i * 1024 + t;
        int pv = 0, rk = -1;
        if (idx < bsize) { pv = pb[idx]; rk = atomicAdd(&cnt[(pv >> 17) & 127], 1); }
        pvA[i] = pv; rkA[i] = rk;
    }
    __syncthreads();
    // wave 0: exclusive prefix over 128 bins, 2 bins/lane, shuffle scan, no barriers
    if (t < 64) {
        int c0 = cnt[t], c1 = cnt[t + 64];
        int v0 = c0, v1 = c1;
        #pragma unroll
        for (int d = 1; d < 64; d <<= 1) {
            int u0 = __shfl_up(v0, d);
            int u1 = __shfl_up(v1, d);
            if (t >= d) { v0 += u0; v1 += u1; }
        }
        int tot0 = __shfl(v0, 63);
        off[t]      = v0 - c0;
        off[t + 64] = v1 - c1 + tot0;
    }
    __syncthreads();
    #pragma unroll
    for (int i = 0; i < 3; ++i) {
        if (rkA[i] >= 0) {
            int bl = (pvA[i] >> 17) & 127;
            srcS[off[bl] + rkA[i]] = pvA[i] & 0x1FFFF;
        }
    }
    __syncthreads();

    int lane = t & 63, wv = t >> 6;          // 16 waves x 8 groups = 128 nodes
    int g8 = lane >> 3, f8 = lane & 7;
    int ln = wv * 8 + g8;                    // this group's node (bucket-local)
    int deg = cnt[ln], base = off[ln];

    float acc[8];
    #pragma unroll
    for (int k = 0; k < 8; ++k) acc[k] = 0.f;

    int j = 0;
    for (; j + 4 <= deg; j += 4) {           // 4 loads in flight per group
        int s0 = srcS[base + j];
        int s1 = srcS[base + j + 1];
        int s2 = srcS[base + j + 2];
        int s3 = srcS[base + j + 3];
        short8 a0 = *(const short8*)(xb + (size_t)s0 * 64 + f8 * 8);
        short8 a1 = *(const short8*)(xb + (size_t)s1 * 64 + f8 * 8);
        short8 a2 = *(const short8*)(xb + (size_t)s2 * 64 + f8 * 8);
        short8 a3 = *(const short8*)(xb + (size_t)s3 * 64 + f8 * 8);
        #pragma unroll
        for (int k = 0; k < 8; ++k) acc[k] += bf2f((unsigned short)a0[k]);
        #pragma unroll
        for (int k = 0; k < 8; ++k) acc[k] += bf2f((unsigned short)a1[k]);
        #pragma unroll
        for (int k = 0; k < 8; ++k) acc[k] += bf2f((unsigned short)a2[k]);
        #pragma unroll
        for (int k = 0; k < 8; ++k) acc[k] += bf2f((unsigned short)a3[k]);
    }
    for (; j < deg; ++j) {
        int s0 = srcS[base + j];
        short8 a0 = *(const short8*)(xb + (size_t)s0 * 64 + f8 * 8);
        #pragma unroll
        for (int k = 0; k < 8; ++k) acc[k] += bf2f((unsigned short)a0[k]);
    }

    {   // agg (mean) -> LDS bf16, row = bucket-local node, stride 72
        float inv = 1.0f / fmaxf((float)deg, 1.0f);
        ushort8 r;
        #pragma unroll
        for (int k = 0; k < 8; ++k) r[k] = f2bf(acc[k] * inv);
        *(ushort8*)(aggS + ln * ASTR + f8 * 8) = r;   // 144-B rows: 16-B aligned
    }
    __syncthreads();

    // ---- linear epilogue: waves 0..7, wave wv -> nodes [g*128+wv*16, +16) ----
    if (wv < 8) {
        int c = lane & 15, q = lane >> 4;
        int nb = g * BN + wv * 16;
        int nm = nb + c; if (nm >= N) nm = N - 1;
        int lnl = wv * 16 + c;               // bucket-local node for aggS

        const short8* WB = (const short8*)WTB;
        v4f acc4[4];
        #pragma unroll
        for (int tt = 0; tt < 4; ++tt) acc4[tt] = 0.f;

        #pragma unroll
        for (int s = 0; s < 2; ++s) {
            short8 af = *(const short8*)(xb + (size_t)nm * 64 + s * 32 + q * 8);
            #pragma unroll
            for (int tt = 0; tt < 4; ++tt)
                acc4[tt] = __builtin_amdgcn_mfma_f32_16x16x32_bf16(
                    af, WB[(s * 4 + tt) * 64 + lane], acc4[tt], 0, 0, 0);
        }
        #pragma unroll
        for (int s = 0; s < 2; ++s) {
            short8 af = *(const short8*)(aggS + lnl * ASTR + s * 32 + q * 8);
            #pragma unroll
            for (int tt = 0; tt < 4; ++tt)
                acc4[tt] = __builtin_amdgcn_mfma_f32_16x16x32_bf16(
                    af, WB[((2 + s) * 4 + tt) * 64 + lane], acc4[tt], 0, 0, 0);
        }

        float bb[4], gg[4], be[4];
        #pragma unroll
        for (int tt = 0; tt < 4; ++tt) {
            bb[tt] = b[tt * 16 + c];
            gg[tt] = gamma[tt * 16 + c];
            be[tt] = beta[tt * 16 + c];
        }
        #pragma unroll
        for (int r = 0; r < 4; ++r) {
            int node = nb + q * 4 + r;
            float v[4]; float s0 = 0.f, q0 = 0.f;
            #pragma unroll
            for (int tt = 0; tt < 4; ++tt) {
                float vv = acc4[tt][r] + bb[tt];
                vv = fmaxf(vv, 0.f);
                v[tt] = vv; s0 += vv; q0 += vv * vv;
            }
            #pragma unroll
            for (int o = 1; o <= 8; o <<= 1) {
                s0 += __shfl_xor(s0, o);
                q0 += __shfl_xor(q0, o);
            }
            float mu  = s0 * (1.0f / 64.0f);
            float var = q0 * (1.0f / 64.0f) - mu * mu;
            float rs  = rsqrtf(var + LN_EPS);
            if (node < N) {
                #pragma unroll
                for (int tt = 0; tt < 4; ++tt)
                    out[(size_t)node * 64 + tt * 16 + c] = (v[tt] - mu) * rs * gg[tt] + be[tt];
            }
        }
    }
}

extern "C" void kernel_launch(void* const* d_in, const int* in_sizes, int n_in,
                              void* d_out, int out_size, void* d_ws, size_t ws_size,
                              hipStream_t stream)
{
    const float* x     = (const float*)d_in[0];
    const int*   ei    = (const int*)d_in[1];
    const float* W     = (const float*)d_in[2];
    const float* b     = (const float*)d_in[3];
    const float* gamma = (const float*)d_in[4];
    const float* beta  = (const float*)d_in[5];

    int N = in_sizes[0] / 64;      // 100000
    int E = in_sizes[1] / 2;       // 1600000

    // ws (ints): cursor1[128] | cursor2[896*8] | WTB[4096] | pairs2[NBK*BC] | xb (bf16)
    int* wsI = (int*)d_ws;
    int* cursor1 = wsI;
    int* cursor2 = wsI + 128;
    unsigned short* WTB = (unsigned short*)(wsI + 128 + 896 * CSTRIDE);
    int* pairs2 = wsI + 128 + 896 * CSTRIDE + 4096;
    unsigned short* xb = (unsigned short*)(pairs2 + (size_t)NBK * BC);

    // pairs1 lives in d_out (7.5 MB of 25.6 MB), dead after bin2; the fused
    // sortgather then overwrites d_out with the final f32 output. ei untouched.
    int* pairs1 = (int*)d_out;
    float* out = (float*)d_out;

    hipMemsetAsync(cursor1, 0, (size_t)(128 + 896 * CSTRIDE) * sizeof(int), stream);

    int b1 = (E + 4095) / 4096;        // 391
    bin1_kernel<<<b1, 256, 0, stream>>>(ei, cursor1, pairs1, W, WTB,
                                        (const float4*)x, (ushort4*)xb, E, N);

    bin2_kernel<<<NSB * CPS, 256, 0, stream>>>(cursor1, pairs1, cursor2, pairs2);

    sortgather_kernel<<<NBK, 1024, 0, stream>>>(cursor2, pairs2, xb, WTB,
                                                b, gamma, beta, out, N);
}

// Round 4
// 164.091 us; speedup vs baseline: 1.2283x; 1.0119x over previous
//
#include <hip/hip_runtime.h>

#define LN_EPS 1e-5f
#define SBSH   14             // superbucket = dst >> 14 (16384 nodes)
#define NSB    7              // ceil(100000 / 16384)
#define CAP1   268288         // per-SB capacity = 131*2048 (mean 262144 + ~13 sigma)
#define CPS    131            // CAP1 / 2048 chunks per SB (bin2 chunking)
#define BN     128            // nodes per final bucket
#define BC     2368           // bucket capacity (mean 2048 + 7 sigma, R8-proven)
#define NBK    782            // ceil(N / BN)
#define CSTRIDE 8
#define ASTR   72             // aggS row stride in bf16 (144 B -> 4-bank row shift, 2-way max)

typedef __attribute__((ext_vector_type(8))) short short8;
typedef __attribute__((ext_vector_type(8))) unsigned short ushort8;
typedef __attribute__((ext_vector_type(4))) float v4f;

__device__ __forceinline__ unsigned short f2bf(float f) {
    union { float f; unsigned u; } v; v.f = f;
    unsigned r = (v.u + 0x7fffu + ((v.u >> 16) & 1u)) >> 16;   // RNE
    return (unsigned short)r;
}
__device__ __forceinline__ float bf2f(unsigned short h) {
    union { unsigned u; float f; } v; v.u = ((unsigned)h) << 16;
    return v.f;
}

// ---------------- bin1: edges -> 7 superbuckets (+ WTB + x->bf16) ----------------
__global__ __launch_bounds__(256) void bin1_kernel(
    const int* __restrict__ ei, int* __restrict__ cursor1,
    int* __restrict__ pairs1, const float* __restrict__ W,
    unsigned short* __restrict__ WTB, const float4* __restrict__ x4,
    ushort4* __restrict__ xb4, int E, int N)
{
    __shared__ int h[64];       // [copy*8 + sb]
    __shared__ int hbase[64];
    int t = threadIdx.x;
    int cp = t & 7;

    if (blockIdx.x == 0) {
        // WTB: frag (s,tt), lane l, elem j <- W[o=tt*16+(l&15)][k=s*32+(l>>4)*8+j]
        for (int i = t; i < 8192; i += 256) {
            int j = i & 7, l = (i >> 3) & 63, st = i >> 9;
            int s = st >> 2, tt = st & 3;
            WTB[i] = f2bf(W[(tt * 16 + (l & 15)) * 128 + s * 32 + (l >> 4) * 8 + j]);
        }
    }
    {   // grid-stride x -> bf16
        int total4 = N * 16;
        for (int i = blockIdx.x * 256 + t; i < total4; i += gridDim.x * 256) {
            float4 v = x4[i];
            ushort4 u;
            u.x = f2bf(v.x); u.y = f2bf(v.y); u.z = f2bf(v.z); u.w = f2bf(v.w);
            xb4[i] = u;
        }
    }

    for (int i = t; i < 64; i += 256) h[i] = 0;
    __syncthreads();
    int e0 = blockIdx.x * 4096;
    int dstA[16], srcA[16], rkA[16];
    #pragma unroll
    for (int i = 0; i < 16; ++i) {
        int e = e0 + i * 256 + t;
        int dst = 0, src = 0, rk = -1;
        if (e < E) {
            dst = ei[e]; src = ei[E + e];
            if ((unsigned)dst < (unsigned)N) {
                rk = atomicAdd(&h[cp * 8 + (dst >> SBSH)], 1);
                if ((unsigned)src >= (unsigned)N) src = 0;   // replay-safe clamp
            } else { dst = 0; }
        }
        dstA[i] = dst; srcA[i] = src; rkA[i] = rk;
    }
    __syncthreads();
    if (t < 8) {    // per sb: total over copies, one global reservation, copy prefixes
        int tot = 0;
        #pragma unroll
        for (int c = 0; c < 8; ++c) tot += h[c * 8 + t];
        int gb = tot ? atomicAdd(&cursor1[t * 16], tot) : 0;
        int run = gb;
        #pragma unroll
        for (int c = 0; c < 8; ++c) { hbase[c * 8 + t] = run; run += h[c * 8 + t]; }
    }
    __syncthreads();
    #pragma unroll
    for (int i = 0; i < 16; ++i) {
        if (rkA[i] >= 0) {
            int sb = dstA[i] >> SBSH;
            int slot = hbase[cp * 8 + sb] + rkA[i];
            if (slot < CAP1)
                pairs1[(size_t)sb * CAP1 + slot] = ((dstA[i] & 16383) << 17) | srcA[i];
        }
    }
}

// ---------------- bin2: superbucket chunk -> 128-node buckets ----------------
__global__ __launch_bounds__(256) void bin2_kernel(
    const int* __restrict__ cursor1, const int* __restrict__ pairs1,
    int* __restrict__ cursor2, int* __restrict__ pairs2)
{
    __shared__ int h[128], hbase[128];
    int t = threadIdx.x;
    int sb = blockIdx.x / CPS;
    int off0 = (blockIdx.x % CPS) * 2048;
    int tot = cursor1[sb * 16]; if (tot > CAP1) tot = CAP1;
    int m = tot - off0;
    if (m <= 0) return;                    // block-uniform
    if (m > 2048) m = 2048;
    if (t < 128) h[t] = 0;
    __syncthreads();
    const int* p1 = pairs1 + (size_t)sb * CAP1 + off0;
    int pvA[8], rkA[8];
    #pragma unroll
    for (int i = 0; i < 8; ++i) {
        int idx = i * 256 + t;
        int pv = 0, rk = -1;
        if (idx < m) { pv = p1[idx]; rk = atomicAdd(&h[(pv >> 24) & 127], 1); }
        pvA[i] = pv; rkA[i] = rk;
    }
    __syncthreads();
    if (t < 128) {
        int c = h[t];
        hbase[t] = c ? atomicAdd(&cursor2[(sb * 128 + t) * CSTRIDE], c) : 0;
    }
    __syncthreads();
    #pragma unroll
    for (int i = 0; i < 8; ++i) {
        if (rkA[i] >= 0) {
            int bl = (pvA[i] >> 24) & 127;
            int g = sb * 128 + bl;
            int slot = hbase[bl] + rkA[i];
            if (g < NBK && slot < BC)
                pairs2[(size_t)g * BC + slot] = pvA[i] & 0xFFFFFF;
        }
    }
}

// ---- fused sortgather + linear + ReLU + LN (v3: deep uniform gather) ----
// Round-3 post-mortem: gather is LATENCY-bound. VGPR_Count=32 (bare minimum:
// 4 short8 bufs + acc) meant only 4 loads in flight per wave, and the per-lane
// branchy loop ran to max-deg with exec-mask divergence anyway. v3: uniform
// masked-FMA loop -- all 8 groups run to the wave-max degree, 8 edges per
// iteration with ALL 8 global loads issued up front (2x in-flight), and the
// in-range predicate folded into v_fmac (m in {0,1}); no divergent branches.
// Clamps keep srcS reads in the initialized region and xb rows < N (garbage
// row x 0 would be NaN-unsafe). ~55 VGPR -> still <=64 so 2 blocks/CU holds.
__global__ __launch_bounds__(1024, 8) void sortgather_kernel(
    const int* __restrict__ cursor2, const int* __restrict__ pairs2,
    const unsigned short* __restrict__ xb, const unsigned short* __restrict__ WTB,
    const float* __restrict__ b, const float* __restrict__ gamma,
    const float* __restrict__ beta, float* __restrict__ out, int N)
{
    __shared__ int srcS[BC];                         // 9.47 KB
    __shared__ int cnt[BN], off[BN];                 // 1 KB
    __shared__ __align__(16) unsigned short aggS[BN * ASTR];   // 18 KB
    int t = threadIdx.x;
    int g = blockIdx.x;
    int bsize = cursor2[g * CSTRIDE]; if (bsize > BC) bsize = BC;
    const int* pb = pairs2 + (size_t)g * BC;

    if (t < BN) cnt[t] = 0;
    __syncthreads();
    // single histogram+rank pass (pb read ONCE; rank kept in registers)
    int pvA[3], rkA[3];
    #pragma unroll
    for (int i = 0; i < 3; ++i) {
        int idx = i * 1024 + t;
        int pv = 0, rk = -1;
        if (idx < bsize) { pv = pb[idx]; rk = atomicAdd(&cnt[(pv >> 17) & 127], 1); }
        pvA[i] = pv; rkA[i] = rk;
    }
    __syncthreads();
    // wave 0: exclusive prefix over 128 bins, 2 bins/lane, shuffle scan, no barriers
    if (t < 64) {
        int c0 = cnt[t], c1 = cnt[t + 64];
        int v0 = c0, v1 = c1;
        #pragma unroll
        for (int d = 1; d < 64; d <<= 1) {
            int u0 = __shfl_up(v0, d);
            int u1 = __shfl_up(v1, d);
            if (t >= d) { v0 += u0; v1 += u1; }
        }
        int tot0 = __shfl(v0, 63);
        off[t]      = v0 - c0;
        off[t + 64] = v1 - c1 + tot0;
    }
    __syncthreads();
    #pragma unroll
    for (int i = 0; i < 3; ++i) {
        if (rkA[i] >= 0) {
            int bl = (pvA[i] >> 17) & 127;
            srcS[off[bl] + rkA[i]] = pvA[i] & 0x1FFFF;
        }
    }
    __syncthreads();

    int lane = t & 63, wv = t >> 6;          // 16 waves x 8 groups = 128 nodes
    int g8 = lane >> 3, f8 = lane & 7;
    int ln = wv * 8 + g8;                    // this group's node (bucket-local)
    int deg = cnt[ln], base = off[ln];

    // wave-uniform trip count = max deg over the wave's 8 groups
    int wm = deg;
    wm = max(wm, __shfl_xor(wm, 8));
    wm = max(wm, __shfl_xor(wm, 16));
    wm = max(wm, __shfl_xor(wm, 32));
    int cl = (deg > 0) ? deg - 1 : 0;        // clamp target inside initialized srcS

    float acc[8];
    #pragma unroll
    for (int k = 0; k < 8; ++k) acc[k] = 0.f;

    const unsigned short* xf = xb + (size_t)f8 * 8;

    for (int j = 0; j < wm; j += 8) {
        short8 a[8];
        #pragma unroll
        for (int k = 0; k < 8; ++k) {        // 8 independent loads issued together
            int jj = j + k; if (jj > cl) jj = cl;
            int s = srcS[base + jj];
            if (s >= N) s = 0;               // garbage row x 0 would be NaN-unsafe
            a[k] = *(const short8*)(xf + (size_t)s * 64);
        }
        #pragma unroll
        for (int k = 0; k < 8; ++k) {
            float m = (j + k < deg) ? 1.f : 0.f;
            #pragma unroll
            for (int e = 0; e < 8; ++e)
                acc[e] = fmaf(m, bf2f((unsigned short)a[k][e]), acc[e]);
        }
    }

    {   // agg (mean) -> LDS bf16, row = bucket-local node, stride 72
        float inv = 1.0f / fmaxf((float)deg, 1.0f);
        ushort8 r;
        #pragma unroll
        for (int k = 0; k < 8; ++k) r[k] = f2bf(acc[k] * inv);
        *(ushort8*)(aggS + ln * ASTR + f8 * 8) = r;   // 144-B rows: 16-B aligned
    }
    __syncthreads();

    // ---- linear epilogue: waves 0..7, wave wv -> nodes [g*128+wv*16, +16) ----
    if (wv < 8) {
        int c = lane & 15, q = lane >> 4;
        int nb = g * BN + wv * 16;
        int nm = nb + c; if (nm >= N) nm = N - 1;
        int lnl = wv * 16 + c;               // bucket-local node for aggS

        const short8* WB = (const short8*)WTB;
        v4f acc4[4];
        #pragma unroll
        for (int tt = 0; tt < 4; ++tt) acc4[tt] = 0.f;

        #pragma unroll
        for (int s = 0; s < 2; ++s) {
            short8 af = *(const short8*)(xb + (size_t)nm * 64 + s * 32 + q * 8);
            #pragma unroll
            for (int tt = 0; tt < 4; ++tt)
                acc4[tt] = __builtin_amdgcn_mfma_f32_16x16x32_bf16(
                    af, WB[(s * 4 + tt) * 64 + lane], acc4[tt], 0, 0, 0);
        }
        #pragma unroll
        for (int s = 0; s < 2; ++s) {
            short8 af = *(const short8*)(aggS + lnl * ASTR + s * 32 + q * 8);
            #pragma unroll
            for (int tt = 0; tt < 4; ++tt)
                acc4[tt] = __builtin_amdgcn_mfma_f32_16x16x32_bf16(
                    af, WB[((2 + s) * 4 + tt) * 64 + lane], acc4[tt], 0, 0, 0);
        }

        float bb[4], gg[4], be[4];
        #pragma unroll
        for (int tt = 0; tt < 4; ++tt) {
            bb[tt] = b[tt * 16 + c];
            gg[tt] = gamma[tt * 16 + c];
            be[tt] = beta[tt * 16 + c];
        }
        #pragma unroll
        for (int r = 0; r < 4; ++r) {
            int node = nb + q * 4 + r;
            float v[4]; float s0 = 0.f, q0 = 0.f;
            #pragma unroll
            for (int tt = 0; tt < 4; ++tt) {
                float vv = acc4[tt][r] + bb[tt];
                vv = fmaxf(vv, 0.f);
                v[tt] = vv; s0 += vv; q0 += vv * vv;
            }
            #pragma unroll
            for (int o = 1; o <= 8; o <<= 1) {
                s0 += __shfl_xor(s0, o);
                q0 += __shfl_xor(q0, o);
            }
            float mu  = s0 * (1.0f / 64.0f);
            float var = q0 * (1.0f / 64.0f) - mu * mu;
            float rs  = rsqrtf(var + LN_EPS);
            if (node < N) {
                #pragma unroll
                for (int tt = 0; tt < 4; ++tt)
                    out[(size_t)node * 64 + tt * 16 + c] = (v[tt] - mu) * rs * gg[tt] + be[tt];
            }
        }
    }
}

extern "C" void kernel_launch(void* const* d_in, const int* in_sizes, int n_in,
                              void* d_out, int out_size, void* d_ws, size_t ws_size,
                              hipStream_t stream)
{
    const float* x     = (const float*)d_in[0];
    const int*   ei    = (const int*)d_in[1];
    const float* W     = (const float*)d_in[2];
    const float* b     = (const float*)d_in[3];
    const float* gamma = (const float*)d_in[4];
    const float* beta  = (const float*)d_in[5];

    int N = in_sizes[0] / 64;      // 100000
    int E = in_sizes[1] / 2;       // 1600000

    // ws (ints): cursor1[128] | cursor2[896*8] | WTB[4096] | pairs2[NBK*BC] | xb (bf16)
    int* wsI = (int*)d_ws;
    int* cursor1 = wsI;
    int* cursor2 = wsI + 128;
    unsigned short* WTB = (unsigned short*)(wsI + 128 + 896 * CSTRIDE);
    int* pairs2 = wsI + 128 + 896 * CSTRIDE + 4096;
    unsigned short* xb = (unsigned short*)(pairs2 + (size_t)NBK * BC);

    // pairs1 lives in d_out (7.5 MB of 25.6 MB), dead after bin2; the fused
    // sortgather then overwrites d_out with the final f32 output. ei untouched.
    int* pairs1 = (int*)d_out;
    float* out = (float*)d_out;

    hipMemsetAsync(cursor1, 0, (size_t)(128 + 896 * CSTRIDE) * sizeof(int), stream);

    int b1 = (E + 4095) / 4096;        // 391
    bin1_kernel<<<b1, 256, 0, stream>>>(ei, cursor1, pairs1, W, WTB,
                                        (const float4*)x, (ushort4*)xb, E, N);

    bin2_kernel<<<NSB * CPS, 256, 0, stream>>>(cursor1, pairs1, cursor2, pairs2);

    sortgather_kernel<<<NBK, 1024, 0, stream>>>(cursor2, pairs2, xb, WTB,
                                                b, gamma, beta, out, N);
}